// Round 14
// baseline (514.685 us; speedup 1.0000x reference)
//
#include <hip/hip_runtime.h>
#include <cstdint>
#include <cstddef>

#define DEV __device__ __forceinline__

// LDS-only barrier: orders LDS (lgkmcnt) but leaves vmem stores in flight.
#define LGKM_BARRIER() asm volatile("s_waitcnt lgkmcnt(0)\n\ts_barrier" ::: "memory")

typedef float f32x4 __attribute__((ext_vector_type(4)));
typedef __bf16 bf16x8 __attribute__((ext_vector_type(8)));
typedef unsigned short u16x8 __attribute__((ext_vector_type(8)));

static constexpr int D = 1024, H = 16, DK = 64, S = 2048, B = 2;
static constexpr int M_TOT = B * S;               // 4096
static constexpr size_t OUT0 = (size_t)M_TOT * D; // floats in `out`

DEV unsigned short f2bf(float f) {
  unsigned x = __builtin_bit_cast(unsigned, f);
  unsigned r = (x + 0x7fffu + ((x >> 16) & 1u)) >> 16; // RTNE
  return (unsigned short)r;
}

DEV float bf2f(unsigned short u) {
  return __builtin_bit_cast(float, (unsigned)u << 16);
}

DEV f32x4 mfma_bf16(bf16x8 a, bf16x8 b, f32x4 c) {
  return __builtin_amdgcn_mfma_f32_16x16x32_bf16(a, b, c, 0, 0, 0);
}

DEV bf16x8 bc(u16x8 u) { return __builtin_bit_cast(bf16x8, u); }

// ---------------------------------------------------------------------------
// Shared GEMM body: C[m,n] = sum_k A[m,k]*W[n,k] + bias[n]  (NT, MFMA bf16)
// A and W both pre-converted bf16 (staging = pure u16x8 copies).
// MODE 0: Q (scaled 0.125) | 1: K | 2: V transposed | 3: fp32 out.
// ---------------------------------------------------------------------------
template <int MODE>
DEV void proj_body(unsigned short* As, unsigned short* Bs,
                   const unsigned short* A, const unsigned short* W,
                   const float* bias, void* dst) {
  constexpr int BM = 128, BK = 32, LDT = 40; // +8 pad (80 B): bank-spread
  const int tid = threadIdx.x;
  const int lane = tid & 63, wave = tid >> 6;
  const int wrow = wave >> 1, wcol = wave & 1;
  const int l15 = lane & 15, kg = lane >> 4;
  const int m0 = blockIdx.y * BM, n0 = blockIdx.x * BM;
  const int srow = tid >> 1, scb = (tid & 1) * 16;

  f32x4 acc[4][4] = {};

  for (int kt = 0; kt < D; kt += BK) {
    {
      const unsigned short* ap = A + (size_t)(m0 + srow) * D + kt + scb;
      *(u16x8*)&As[srow * LDT + scb] = *(const u16x8*)ap;
      *(u16x8*)&As[srow * LDT + scb + 8] = *(const u16x8*)(ap + 8);

      const unsigned short* wp = W + (size_t)(n0 + srow) * D + kt + scb;
      *(u16x8*)&Bs[srow * LDT + scb] = *(const u16x8*)wp;
      *(u16x8*)&Bs[srow * LDT + scb + 8] = *(const u16x8*)(wp + 8);
    }
    __syncthreads();

    bf16x8 a[4], b[4];
#pragma unroll
    for (int i = 0; i < 4; i++)
      a[i] = bc(*(const u16x8*)&As[(wrow * 64 + i * 16 + l15) * LDT + kg * 8]);
#pragma unroll
    for (int i = 0; i < 4; i++)
      b[i] = bc(*(const u16x8*)&Bs[(wcol * 64 + i * 16 + l15) * LDT + kg * 8]);
#pragma unroll
    for (int mi = 0; mi < 4; mi++)
#pragma unroll
      for (int ni = 0; ni < 4; ni++) acc[mi][ni] = mfma_bf16(a[mi], b[ni], acc[mi][ni]);
    __syncthreads();
  }

#pragma unroll
  for (int mi = 0; mi < 4; mi++) {
#pragma unroll
    for (int ni = 0; ni < 4; ni++) {
      const int n = n0 + wcol * 64 + ni * 16 + l15;
      const float bval = bias[n];
#pragma unroll
      for (int r = 0; r < 4; r++) {
        const int m = m0 + wrow * 64 + mi * 16 + kg * 4 + r;
        float v = acc[mi][ni][r] + bval;
        if constexpr (MODE == 0) v *= 0.125f; // fold 1/sqrt(dk) into Q
        if constexpr (MODE == 0 || MODE == 1) {
          const int b_ = m >> 11, s = m & (S - 1), h = n >> 6, d_ = n & (DK - 1);
          ((unsigned short*)dst)[(((size_t)(b_ * H + h)) * S + s) * DK + d_] = f2bf(v);
        } else if constexpr (MODE == 2) {
          const int b_ = m >> 11, s = m & (S - 1), h = n >> 6, d_ = n & (DK - 1);
          ((unsigned short*)dst)[(((size_t)(b_ * H + h)) * DK + d_) * S + s] = f2bf(v);
        } else {
          ((float*)dst)[(size_t)m * D + n] = v;
        }
      }
    }
  }
}

// ---------------------------------------------------------------------------
// K0: conv — fp32->bf16 for {Wq,Wk,Wv,Wo, query,key,value} + mask bitpack.
// ---------------------------------------------------------------------------
struct ConvArgs {
  const float* src[7];
  unsigned short* dst[7];
  const int* mask;
  unsigned long long* bits;
};

__global__ __launch_bounds__(256) void conv_kernel(ConvArgs ca) {
  const int gid = blockIdx.x, tid = threadIdx.x;
  if (gid < 1024) {
    int seg, local;
    if (gid < 256) { seg = gid >> 6; local = gid & 63; }              // weights
    else { seg = 4 + ((gid - 256) >> 8); local = (gid - 256) & 255; } // inputs
    const float* src = ca.src[seg];
    unsigned short* dst = ca.dst[seg];
    const size_t off = (size_t)local * 16384;
#pragma unroll
    for (int it = 0; it < 4; it++) {
      const size_t i0 = off + it * 4096 + (size_t)tid * 16;
      float4 v0 = *(const float4*)(src + i0);
      float4 v1 = *(const float4*)(src + i0 + 4);
      float4 v2 = *(const float4*)(src + i0 + 8);
      float4 v3 = *(const float4*)(src + i0 + 12);
      u16x8 t0, t1;
      t0[0] = f2bf(v0.x); t0[1] = f2bf(v0.y); t0[2] = f2bf(v0.z); t0[3] = f2bf(v0.w);
      t0[4] = f2bf(v1.x); t0[5] = f2bf(v1.y); t0[6] = f2bf(v1.z); t0[7] = f2bf(v1.w);
      t1[0] = f2bf(v2.x); t1[1] = f2bf(v2.y); t1[2] = f2bf(v2.z); t1[3] = f2bf(v2.w);
      t1[4] = f2bf(v3.x); t1[5] = f2bf(v3.y); t1[6] = f2bf(v3.z); t1[7] = f2bf(v3.w);
      *(u16x8*)(dst + i0) = t0;
      *(u16x8*)(dst + i0 + 8) = t1;
    }
  } else {
    const int lane = tid & 63;
    const int base = (gid - 1024) * 256;
    for (int w = base + (tid >> 6); w < base + 256; w += 4) {
      int m = __builtin_nontemporal_load(ca.mask + (size_t)w * 64 + lane);
      unsigned long long bal = __ballot(m != 0);
      if (lane == 0) ca.bits[w] = bal;
    }
  }
}

// ---------------------------------------------------------------------------
// K1: QKV projection GEMMs (z selects), A and W pre-converted bf16.
// ---------------------------------------------------------------------------
struct GemmArgs {
  const unsigned short* Ab[3];
  const unsigned short* Wb[3];
  const float* bias[3];
  unsigned short* dst[3];
};

__global__ __launch_bounds__(256) void qkv_gemm(GemmArgs ga) {
  __shared__ __align__(16) unsigned short As[128 * 40];
  __shared__ __align__(16) unsigned short Bs[128 * 40];
  const int z = blockIdx.z;
  if (z == 0)
    proj_body<0>(As, Bs, ga.Ab[0], ga.Wb[0], ga.bias[0], ga.dst[0]);
  else if (z == 1)
    proj_body<1>(As, Bs, ga.Ab[1], ga.Wb[1], ga.bias[1], ga.dst[1]);
  else
    proj_body<2>(As, Bs, ga.Ab[2], ga.Wb[2], ga.bias[2], ga.dst[2]);
}

// ---------------------------------------------------------------------------
// K2: output projection (A = ctx bf16, W = Wob bf16)
// ---------------------------------------------------------------------------
__global__ __launch_bounds__(256) void out_proj(const unsigned short* __restrict__ ctx,
                                                const unsigned short* __restrict__ Wob,
                                                const float* __restrict__ bo,
                                                float* __restrict__ out) {
  __shared__ __align__(16) unsigned short As[128 * 40];
  __shared__ __align__(16) unsigned short Bs[128 * 40];
  proj_body<3>(As, Bs, ctx, Wob, bo, out);
}

// ---------------------------------------------------------------------------
// K3: fused attention, occupancy-max variant.
// 256 thr (4 waves), QB=16 q-rows/WG, ~17.5 KB LDS, launch_bounds(256,4)
// (VGPR cap 128 >= natural ~52 — NEVER cap below natural: R8/R9 spills).
// If allocator lands <=64 VGPR: 8 WG/CU = 32 waves = 100% occupancy (4x the
// R10-R13 residency; occupancy was the only knob that ever moved attn).
// Pass 1: QK^T -> sum(exp) -> rinv. Pass 2: 8 superblocks x 256 cols:
// [writeDuty(sb-1) | compute sb] LGKM [PV sb]. PV: wave = d-group, full K.
// ---------------------------------------------------------------------------
__global__ __launch_bounds__(256, 4) void attn_kernel(
    const unsigned short* __restrict__ Qb, const unsigned short* __restrict__ Kb,
    const unsigned short* __restrict__ Vt, const unsigned* __restrict__ bits32,
    float* __restrict__ attn_out, unsigned short* __restrict__ ctx) {
  constexpr int QB = 16;
  constexpr int PROW = 264; // u16; 528 B row stride
  __shared__ __align__(16) unsigned short pbuf[2][QB * PROW]; // 16896 B
  __shared__ float rsum[4 * QB];                              // 256 B
  __shared__ float rinv_s[QB];
  __shared__ unsigned mflag;

  const int wg = blockIdx.x;
  const int qblk = wg & 127, h = (wg >> 7) & 15, b_ = wg >> 11;
  const int bh = b_ * H + h;
  const int qb0 = qblk * QB;
  const int tid = threadIdx.x, lane = tid & 63, wave = tid >> 6;
  const int l15 = lane & 15, kg = lane >> 4;
  const int rowq = kg * 4;
  constexpr float LOG2E = 1.44269504088896340736f;

  const unsigned* mrow = bits32 + ((size_t)b_ * S + qb0) * 64; // 16 rows x 64 words

  // ---- all-ones flag (4 direct global reads/thread, LDS atomicAnd) ----
  if (tid == 0) mflag = 1u;
  __syncthreads();
  {
    unsigned ok = 1u;
#pragma unroll
    for (int i = 0; i < 4; i++)
      ok &= (mrow[tid + i * 256] == 0xFFFFFFFFu) ? 1u : 0u;
    if (!ok) atomicAnd(&mflag, 0u);
  }

  const unsigned short* qbase = Qb + ((size_t)bh * S + qb0) * DK;
  bf16x8 aq0 = bc(*(const u16x8*)(qbase + (size_t)l15 * DK + kg * 8));
  bf16x8 aq1 = bc(*(const u16x8*)(qbase + (size_t)l15 * DK + 32 + kg * 8));
  __syncthreads();
  const bool allones = (mflag != 0u); // block-uniform

  // ---- pass 1: QK^T -> e=exp(s) -> row sums only (32 tiles/wave) ----
  float sum[4] = {0.f, 0.f, 0.f, 0.f};
#pragma unroll 2
  for (int i = 0; i < 32; i++) {
    const int t = wave * 32 + i; // 16-col tile 0..127
    const unsigned short* krow = Kb + ((size_t)bh * S + t * 16 + l15) * DK;
    bf16x8 b0 = bc(*(const u16x8*)(krow + kg * 8));
    bf16x8 b1 = bc(*(const u16x8*)(krow + 32 + kg * 8));
    const unsigned shift = (unsigned)((t & 1) * 16 + l15);
    f32x4 c = {0.f, 0.f, 0.f, 0.f};
    c = mfma_bf16(aq0, b0, c);
    c = mfma_bf16(aq1, b1, c);
    if (allones) {
#pragma unroll
      for (int r = 0; r < 4; r++) sum[r] += exp2f(c[r] * LOG2E);
    } else {
#pragma unroll
      for (int r = 0; r < 4; r++) {
        const unsigned w = mrow[(rowq + r) * 64 + (t >> 1)];
        sum[r] += ((w >> shift) & 1u) ? exp2f(c[r] * LOG2E) : 0.f;
      }
    }
  }

  // reduce sums across the 16 col-lanes, then across 4 waves
#pragma unroll
  for (int r = 0; r < 4; r++) {
    float s = sum[r];
    s += __shfl_xor(s, 1);
    s += __shfl_xor(s, 2);
    s += __shfl_xor(s, 4);
    s += __shfl_xor(s, 8);
    if (l15 == 0) rsum[wave * QB + rowq + r] = s;
  }
  __syncthreads();
  if (tid < QB) {
    float t2 = 0.f;
#pragma unroll
    for (int w = 0; w < 4; w++) t2 += rsum[w * QB + tid];
    rinv_s[tid] = 1.f / t2;
  }
  __syncthreads();

  float ri[4];
#pragma unroll
  for (int r = 0; r < 4; r++) ri[r] = rinv_s[rowq + r];

  // ---- pass 2, pipelined: [store sb-1 | compute sb] LGKM [PV sb] ----
  const int dg = wave; // PV d-group; full K per wave (no combine)
  const unsigned short* vrow = Vt + ((size_t)bh * DK + dg * 16 + l15) * S;
  float* abase = attn_out + ((size_t)bh * S + qb0) * S;
  const int wrow2 = lane >> 5;      // writer duty: row parity
  const int wcol = (lane & 31) * 8; // writer duty: col
  f32x4 o = {0.f, 0.f, 0.f, 0.f};

  auto writeDuty = [&](int sbw) {
    const unsigned short* pb = pbuf[sbw & 1];
#pragma unroll
    for (int rr = 0; rr < 2; rr++) {
      const int row = wave * 4 + rr * 2 + wrow2;
      u16x8 u = *(const u16x8*)&pb[row * PROW + wcol];
      f32x4 lo, hi;
      lo[0] = bf2f(u[0]); lo[1] = bf2f(u[1]); lo[2] = bf2f(u[2]); lo[3] = bf2f(u[3]);
      hi[0] = bf2f(u[4]); hi[1] = bf2f(u[5]); hi[2] = bf2f(u[6]); hi[3] = bf2f(u[7]);
      float* dp = abase + (size_t)row * S + sbw * 256 + wcol;
      __builtin_nontemporal_store(lo, (f32x4*)dp);
      __builtin_nontemporal_store(hi, (f32x4*)(dp + 4));
    }
  };

  for (int sb = 0; sb < 8; sb++) {
    if (sb) writeDuty(sb - 1); // stores drain during compute below

    unsigned short* pb = pbuf[sb & 1];
#pragma unroll
    for (int j = 0; j < 4; j++) {
      const int t = sb * 16 + wave * 4 + j;
      const unsigned short* krow = Kb + ((size_t)bh * S + t * 16 + l15) * DK;
      bf16x8 b0 = bc(*(const u16x8*)(krow + kg * 8));
      bf16x8 b1 = bc(*(const u16x8*)(krow + 32 + kg * 8));
      const unsigned shift = (unsigned)((t & 1) * 16 + l15);
      const int lc = (wave * 4 + j) * 16 + l15; // local col 0..255
      f32x4 c = {0.f, 0.f, 0.f, 0.f};
      c = mfma_bf16(aq0, b0, c);
      c = mfma_bf16(aq1, b1, c);
      if (allones) {
#pragma unroll
        for (int r = 0; r < 4; r++)
          pb[(rowq + r) * PROW + lc] = f2bf(exp2f(c[r] * LOG2E) * ri[r]);
      } else {
#pragma unroll
        for (int r = 0; r < 4; r++) {
          const unsigned w = mrow[(rowq + r) * 64 + (t >> 1)];
          const float e = ((w >> shift) & 1u) ? exp2f(c[r] * LOG2E) : 0.f;
          pb[(rowq + r) * PROW + lc] = f2bf(e * ri[r]);
        }
      }
    }
    LGKM_BARRIER(); // LDS-only: NT stores stay in flight

    // PV duty: wave = d-group, 256 cols of this superblock, full K share
    const unsigned short* vv = vrow + sb * 256;
#pragma unroll
    for (int ks = 0; ks < 8; ks++) {
      bf16x8 bv = bc(*(const u16x8*)(vv + ks * 32 + kg * 8));
      bf16x8 af = bc(*(const u16x8*)&pb[l15 * PROW + ks * 32 + kg * 8]);
      o = mfma_bf16(af, bv, o);
    }
  }
  writeDuty(7); // tail stores

  // ---- ctx write (o already normalized; no cross-wave combine) ----
#pragma unroll
  for (int r = 0; r < 4; r++) {
    const int row = rowq + r;
    ctx[((size_t)(b_ * S + qb0 + row)) * D + h * DK + dg * 16 + l15] = f2bf(o[r]);
  }
}

// ---------------------------------------------------------------------------
extern "C" void kernel_launch(void* const* d_in, const int* in_sizes, int n_in,
                              void* d_out, int out_size, void* d_ws, size_t ws_size,
                              hipStream_t stream) {
  const float* query = (const float*)d_in[0];
  const float* key   = (const float*)d_in[1];
  const float* value = (const float*)d_in[2];
  const int*   mask  = (const int*)d_in[3];
  const float* Wq = (const float*)d_in[4];
  const float* bq = (const float*)d_in[5];
  const float* Wk = (const float*)d_in[6];
  const float* bk = (const float*)d_in[7];
  const float* Wv = (const float*)d_in[8];
  const float* bv = (const float*)d_in[9];
  const float* Wo = (const float*)d_in[10];
  const float* bo = (const float*)d_in[11];

  float* out_p = (float*)d_out;
  float* attn_p = (float*)d_out + OUT0;

  size_t off = 0;
  auto carve = [&](size_t bytes) {
    void* p = (char*)d_ws + off;
    off += (bytes + 255) & ~(size_t)255;
    return p;
  };
  const size_t headed = (size_t)B * H * S * DK * sizeof(unsigned short); // 8 MB
  const size_t wbytes = (size_t)D * D * sizeof(unsigned short);          // 2 MB
  const size_t inbytes = (size_t)M_TOT * D * sizeof(unsigned short);     // 8 MB
  unsigned short* Qb = (unsigned short*)carve(headed);
  unsigned short* Kb = (unsigned short*)carve(headed);
  unsigned short* Vt = (unsigned short*)carve(headed);
  unsigned short* ctx = (unsigned short*)carve(inbytes);
  unsigned long long* bits = (unsigned long long*)carve((size_t)B * S * S / 8);
  unsigned short* Wqb = (unsigned short*)carve(wbytes);
  unsigned short* Wkb = (unsigned short*)carve(wbytes);
  unsigned short* Wvb = (unsigned short*)carve(wbytes);
  unsigned short* Wob = (unsigned short*)carve(wbytes);
  unsigned short* Qin = (unsigned short*)carve(inbytes);
  unsigned short* Kin = (unsigned short*)carve(inbytes);
  unsigned short* Vin = (unsigned short*)carve(inbytes);

  ConvArgs ca;
  ca.src[0] = Wq; ca.src[1] = Wk; ca.src[2] = Wv; ca.src[3] = Wo;
  ca.src[4] = query; ca.src[5] = key; ca.src[6] = value;
  ca.dst[0] = Wqb; ca.dst[1] = Wkb; ca.dst[2] = Wvb; ca.dst[3] = Wob;
  ca.dst[4] = Qin; ca.dst[5] = Kin; ca.dst[6] = Vin;
  ca.mask = mask; ca.bits = bits;
  conv_kernel<<<1536, 256, 0, stream>>>(ca);

  GemmArgs ga;
  ga.Ab[0] = Qin; ga.Ab[1] = Kin; ga.Ab[2] = Vin;
  ga.Wb[0] = Wqb; ga.Wb[1] = Wkb; ga.Wb[2] = Wvb;
  ga.bias[0] = bq; ga.bias[1] = bk; ga.bias[2] = bv;
  ga.dst[0] = Qb; ga.dst[1] = Kb; ga.dst[2] = Vt;
  qkv_gemm<<<dim3(8, 32, 3), 256, 0, stream>>>(ga);

  attn_kernel<<<B * H * (S / 16), 256, 0, stream>>>(Qb, Kb, Vt, (const unsigned*)bits,
                                                    attn_p, ctx);

  out_proj<<<dim3(8, 32), 256, 0, stream>>>(ctx, Wob, bo, out_p);
}